// Round 2
// baseline (10049.140 us; speedup 1.0000x reference)
//
#include <hip/hip_runtime.h>

typedef _Float16 f16;
typedef _Float16 f16x8 __attribute__((ext_vector_type(8)));
typedef float f32x4 __attribute__((ext_vector_type(4)));

#define H_    256
#define TB_   128     // batch rows per workgroup
#define NT_   512     // threads per workgroup
#define SORB_ 64

#define MFMA16(a, b, c) __builtin_amdgcn_mfma_f32_16x16x32_f16((a), (b), (c), 0, 0, 0)

__device__ __forceinline__ float sigm(float v) { return 1.0f / (1.0f + __expf(-v)); }
__device__ __forceinline__ float tanh_fast(float v) {
  float a = fabsf(v);
  float e = __expf(-2.0f * a);            // e <= 1, no overflow possible
  float t = (1.0f - e) / (1.0f + e);
  return copysignf(t, v);
}
// XOR-swizzled LDS index for h tiles (f16 units, 16B-unit swizzle -> conflict-free b128 reads)
__device__ __forceinline__ int hswz(int row, int col) {
  return row * H_ + (col ^ ((row & 7) << 3));
}

// fp32 -> f16 weight conversion: [whh0 | wih1 | whh1], each [768][256] row-major
__global__ void wcvt(const float* __restrict__ a, const float* __restrict__ b,
                     const float* __restrict__ c, f16* __restrict__ o) {
  int i = blockIdx.x * 256 + threadIdx.x;
  const int n = 768 * 256;
  if (i < n) {
    o[i]         = (f16)a[i];
    o[n + i]     = (f16)b[i];
    o[2 * n + i] = (f16)c[i];
  }
}

__global__ __launch_bounds__(NT_, 2) void rnnwf(
    const int* __restrict__ x,
    const float* __restrict__ w_ih0, const float* __restrict__ b_ih0,
    const float* __restrict__ b_hh0, const float* __restrict__ b_ih1,
    const float* __restrict__ b_hh1, const float* __restrict__ w_amp,
    const float* __restrict__ b_amp, const f16* __restrict__ W16,
    float* __restrict__ out)
{
  __shared__ __align__(16) f16 h0s[TB_ * H_];   // 64 KB, swizzled
  __shared__ __align__(16) f16 h1s[TB_ * H_];   // 64 KB, swizzled
  __shared__ float gi0T[3 * 768];   // [case 0=prime,1=bit0,2=bit1][768]; b_hh0 folded for j<512
  __shared__ float bhh0n[256];
  __shared__ float bsum1[768];      // b_ih1 + b_hh1 for j<512; b_ih1 for j>=512
  __shared__ float bhh1n[256];
  __shared__ float wampL[512];
  __shared__ float bampL[2];
  __shared__ unsigned short bitsL[TB_ * 4];     // 16 bits per quarter-row

  const int tid  = threadIdx.x;
  const int wave = tid >> 6;
  const int lane = tid & 63;
  const int l15  = lane & 15;
  const int lg   = lane >> 4;                 // 0..3
  const int rowbase = blockIdx.x * TB_;

  // ---- one-time table setup ----
  for (int j = tid; j < 768; j += NT_) {
    float bi = b_ih0[j], bh = b_hh0[j];
    float base = bi + (j < 512 ? bh : 0.0f);
    gi0T[j]        = base;                       // priming: zero input
    gi0T[768 + j]  = base + w_ih0[2 * j + 0];    // bit 0
    gi0T[1536 + j] = base + w_ih0[2 * j + 1];    // bit 1
    if (j >= 512) bhh0n[j - 512] = bh;
    bsum1[j] = b_ih1[j] + (j < 512 ? b_hh1[j] : 0.0f);
    if (j >= 512) bhh1n[j - 512] = b_hh1[j];
  }
  for (int j = tid; j < 512; j += NT_) wampL[j] = w_amp[j];
  if (tid < 2) bampL[tid] = b_amp[tid];
  {
    int row = tid >> 2, q = tid & 3;
    const int* xp = x + (size_t)(rowbase + row) * SORB_ + q * 16;
    unsigned m = 0;
    #pragma unroll
    for (int i = 0; i < 16; ++i) m |= (unsigned)(xp[i] & 1) << i;
    bitsL[row * 4 + q] = (unsigned short)m;
  }
  for (int i = tid; i < TB_ * H_; i += NT_) { h0s[i] = (f16)0.f; h1s[i] = (f16)0.f; }
  __syncthreads();

  float prob = 1.0f;
  const f16* Wih1 = W16 + 768 * 256;
  const f16* Whh1 = W16 + 2 * 768 * 256;

  for (int t = -1; t < SORB_; ++t) {
    // ================= layer 0 =================
    for (int mh = 0; mh < 2; ++mh) {          // M-half: rows [mh*64, mh*64+64)
      f32x4 sv[8];                             // staged h0_new, fp32, static-indexed [nt*4+m]
      #pragma unroll
      for (int nt = 0; nt < 2; ++nt) {
        const int col = wave * 32 + nt * 16 + l15;   // hidden-unit index 0..255
        f32x4 aR[4], aZ[4], aN[4];
        #pragma unroll
        for (int m = 0; m < 4; ++m) { aR[m] = (f32x4){0,0,0,0}; aZ[m] = aR[m]; aN[m] = aR[m]; }
        #pragma unroll
        for (int kt = 0; kt < 8; ++kt) {
          const int k0 = kt * 32 + lg * 8;
          const f16* wb = W16 + (size_t)col * 256 + k0;      // r-gate row = col
          f16x8 Br = *(const f16x8*)(wb);
          f16x8 Bz = *(const f16x8*)(wb + 256 * 256);
          f16x8 Bn = *(const f16x8*)(wb + 512 * 256);
          #pragma unroll
          for (int m = 0; m < 4; ++m) {
            const int arow = mh * 64 + m * 16 + l15;
            f16x8 A = *(const f16x8*)&h0s[hswz(arow, k0)];
            aR[m] = MFMA16(A, Br, aR[m]);
            aZ[m] = MFMA16(A, Bz, aZ[m]);
            aN[m] = MFMA16(A, Bn, aN[m]);
          }
        }
        #pragma unroll
        for (int m = 0; m < 4; ++m) {
          #pragma unroll
          for (int e = 0; e < 4; ++e) {
            const int row = mh * 64 + m * 16 + lg * 4 + e;   // D: row=(l>>4)*4+reg, col=l&15
            int cse = 0;
            if (t >= 0) cse = 1 + ((bitsL[row * 4 + (t >> 4)] >> (t & 15)) & 1);
            const float* gt = &gi0T[cse * 768];
            float r  = sigm(aR[m][e] + gt[col]);
            float z  = sigm(aZ[m][e] + gt[256 + col]);
            float hn = aN[m][e] + bhh0n[col];
            float n  = tanh_fast(gt[512 + col] + r * hn);
            float ho = (float)h0s[hswz(row, col)];
            sv[nt * 4 + m][e] = (1.0f - z) * n + z * ho;
          }
        }
      }
      __syncthreads();                         // all A-reads of this half done
      #pragma unroll
      for (int nt = 0; nt < 2; ++nt) {
        const int col = wave * 32 + nt * 16 + l15;
        #pragma unroll
        for (int m = 0; m < 4; ++m)
          #pragma unroll
          for (int e = 0; e < 4; ++e) {
            const int row = mh * 64 + m * 16 + lg * 4 + e;
            h0s[hswz(row, col)] = (f16)sv[nt * 4 + m][e];
          }
      }
      __syncthreads();
    }

    // ================= layer 1 =================
    for (int mh = 0; mh < 2; ++mh) {
      f32x4 sv[8];
      #pragma unroll
      for (int nt = 0; nt < 2; ++nt) {
        const int col = wave * 32 + nt * 16 + l15;
        f32x4 aR[4], aZ[4], aI[4], aHn[4];
        #pragma unroll
        for (int m = 0; m < 4; ++m) { aR[m] = (f32x4){0,0,0,0}; aZ[m] = aR[m]; aI[m] = aR[m]; aHn[m] = aR[m]; }
        #pragma unroll
        for (int kt = 0; kt < 8; ++kt) {
          const int k0 = kt * 32 + lg * 8;
          const f16* wi = Wih1 + (size_t)col * 256 + k0;
          const f16* wh = Whh1 + (size_t)col * 256 + k0;
          f16x8 BiR = *(const f16x8*)(wi);
          f16x8 BiZ = *(const f16x8*)(wi + 256 * 256);
          f16x8 BiN = *(const f16x8*)(wi + 512 * 256);
          f16x8 BhR = *(const f16x8*)(wh);
          f16x8 BhZ = *(const f16x8*)(wh + 256 * 256);
          f16x8 BhN = *(const f16x8*)(wh + 512 * 256);
          #pragma unroll
          for (int m = 0; m < 4; ++m) {
            const int arow = mh * 64 + m * 16 + l15;
            f16x8 A0 = *(const f16x8*)&h0s[hswz(arow, k0)];  // h0_new
            f16x8 A1 = *(const f16x8*)&h1s[hswz(arow, k0)];  // h1_old
            aR[m]  = MFMA16(A0, BiR, aR[m]);  aR[m] = MFMA16(A1, BhR, aR[m]);
            aZ[m]  = MFMA16(A0, BiZ, aZ[m]);  aZ[m] = MFMA16(A1, BhZ, aZ[m]);
            aI[m]  = MFMA16(A0, BiN, aI[m]);
            aHn[m] = MFMA16(A1, BhN, aHn[m]);
          }
        }
        #pragma unroll
        for (int m = 0; m < 4; ++m) {
          #pragma unroll
          for (int e = 0; e < 4; ++e) {
            float r = sigm(aR[m][e] + bsum1[col]);
            float z = sigm(aZ[m][e] + bsum1[256 + col]);
            float n = tanh_fast(aI[m][e] + bsum1[512 + col] + r * (aHn[m][e] + bhh1n[col]));
            const int row = mh * 64 + m * 16 + lg * 4 + e;
            float ho = (float)h1s[hswz(row, col)];
            sv[nt * 4 + m][e] = (1.0f - z) * n + z * ho;
          }
        }
      }
      __syncthreads();
      #pragma unroll
      for (int nt = 0; nt < 2; ++nt) {
        const int col = wave * 32 + nt * 16 + l15;
        #pragma unroll
        for (int m = 0; m < 4; ++m)
          #pragma unroll
          for (int e = 0; e < 4; ++e) {
            const int row = mh * 64 + m * 16 + lg * 4 + e;
            h1s[hswz(row, col)] = (f16)sv[nt * 4 + m][e];
          }
      }
      __syncthreads();
    }

    // ================= amplitude head =================
    if (t >= 0) {
      const int row = tid >> 2;
      const int t4  = tid & 3;
      float d0 = 0.f, d1 = 0.f;
      #pragma unroll
      for (int kk = 0; kk < 64; kk += 8) {
        const int k0 = t4 * 64 + kk;
        f16x8 hv = *(const f16x8*)&h1s[hswz(row, k0)];
        #pragma unroll
        for (int i = 0; i < 8; ++i) {
          float hf = (float)hv[i];
          d0 = fmaf(hf, wampL[k0 + i], d0);
          d1 = fmaf(hf, wampL[256 + k0 + i], d1);
        }
      }
      d0 += __shfl_xor(d0, 1); d0 += __shfl_xor(d0, 2);
      d1 += __shfl_xor(d1, 1); d1 += __shfl_xor(d1, 2);
      const int bit = (bitsL[row * 4 + (t >> 4)] >> (t & 15)) & 1;
      float diff = (d0 + bampL[0]) - (d1 + bampL[1]);
      if (bit) diff = -diff;
      prob *= 1.0f / (1.0f + __expf(-diff));   // softmax over 2 = sigmoid of logit diff
    }
  }

  if ((tid & 3) == 0) out[rowbase + (tid >> 2)] = sqrtf(prob);
}

extern "C" void kernel_launch(void* const* d_in, const int* in_sizes, int n_in,
                              void* d_out, int out_size, void* d_ws, size_t ws_size,
                              hipStream_t stream) {
  const int*   x     = (const int*)d_in[0];
  const float* w_ih0 = (const float*)d_in[1];
  const float* w_hh0 = (const float*)d_in[2];
  const float* b_ih0 = (const float*)d_in[3];
  const float* b_hh0 = (const float*)d_in[4];
  const float* w_ih1 = (const float*)d_in[5];
  const float* w_hh1 = (const float*)d_in[6];
  const float* b_ih1 = (const float*)d_in[7];
  const float* b_hh1 = (const float*)d_in[8];
  const float* w_amp = (const float*)d_in[9];
  const float* b_amp = (const float*)d_in[10];
  (void)in_sizes; (void)n_in; (void)out_size; (void)ws_size;

  f16* W16 = (f16*)d_ws;   // needs 3*768*256*2 = 1.18 MB of workspace
  hipLaunchKernelGGL(wcvt, dim3(768), dim3(256), 0, stream, w_hh0, w_ih1, w_hh1, W16);
  hipLaunchKernelGGL(rnnwf, dim3(256), dim3(NT_), 0, stream,
                     x, w_ih0, b_ih0, b_hh0, b_ih1, b_hh1, w_amp, b_amp, W16,
                     (float*)d_out);
}

// Round 3
// 9417.817 us; speedup vs baseline: 1.0670x; 1.0670x over previous
//
#include <hip/hip_runtime.h>

typedef _Float16 f16;
typedef _Float16 f16x8 __attribute__((ext_vector_type(8)));
typedef _Float16 f16x4 __attribute__((ext_vector_type(4)));
typedef float f32x4 __attribute__((ext_vector_type(4)));

#define H_    256
#define TB_   128     // batch rows per workgroup
#define NT_   512     // threads per workgroup
#define SORB_ 64

#define MFMA16(a, b, c) __builtin_amdgcn_mfma_f32_16x16x32_f16((a), (b), (c), 0, 0, 0)

__device__ __forceinline__ float sigm(float v) { return 1.0f / (1.0f + __expf(-v)); }
__device__ __forceinline__ float tanh_fast(float v) {
  float a = fabsf(v);
  float e = __expf(-2.0f * a);            // e <= 1, no overflow possible
  float t = (1.0f - e) / (1.0f + e);
  return copysignf(t, v);
}
// XOR-swizzled LDS index for h tiles (f16 units, 16B-unit swizzle -> conflict-free b128 reads)
__device__ __forceinline__ int hswz(int row, int col) {
  return row * H_ + (col ^ ((row & 7) << 3));
}

// fp32 -> f16 weight conversion: [whh0 | wih1 | whh1], each [768][256] row-major
__global__ void wcvt(const float* __restrict__ a, const float* __restrict__ b,
                     const float* __restrict__ c, f16* __restrict__ o) {
  int i = blockIdx.x * 256 + threadIdx.x;
  const int n = 768 * 256;
  if (i < n) {
    o[i]         = (f16)a[i];
    o[n + i]     = (f16)b[i];
    o[2 * n + i] = (f16)c[i];
  }
}

__global__ __launch_bounds__(NT_, 1) void rnnwf(
    const int* __restrict__ x,
    const float* __restrict__ w_ih0, const float* __restrict__ b_ih0,
    const float* __restrict__ b_hh0, const float* __restrict__ b_ih1,
    const float* __restrict__ b_hh1, const float* __restrict__ w_amp,
    const float* __restrict__ b_amp, const f16* __restrict__ W16,
    float* __restrict__ out)
{
  __shared__ __align__(16) f16 h0s[TB_ * H_];   // 64 KB, swizzled
  __shared__ __align__(16) f16 h1s[TB_ * H_];   // 64 KB, swizzled
  __shared__ float gi0T[3 * 768];   // [case 0=prime,1=bit0,2=bit1][768]; b_hh0 folded for j<512
  __shared__ float bhh0n[256];
  __shared__ float bsum1[768];      // b_ih1 + b_hh1 for j<512; b_ih1 for j>=512
  __shared__ float bhh1n[256];
  __shared__ float wampL[512];
  __shared__ float bampL[2];
  __shared__ unsigned short bitsL[TB_ * 4];     // 16 bits per quarter-row

  const int tid  = threadIdx.x;
  const int wave = tid >> 6;
  const int lane = tid & 63;
  const int l15  = lane & 15;
  const int lg   = lane >> 4;                 // 0..3
  const int rowbase = blockIdx.x * TB_;

  // ---- one-time table setup ----
  for (int j = tid; j < 768; j += NT_) {
    float bi = b_ih0[j], bh = b_hh0[j];
    float base = bi + (j < 512 ? bh : 0.0f);
    gi0T[j]        = base;                       // priming: zero input
    gi0T[768 + j]  = base + w_ih0[2 * j + 0];    // bit 0
    gi0T[1536 + j] = base + w_ih0[2 * j + 1];    // bit 1
    if (j >= 512) bhh0n[j - 512] = bh;
    bsum1[j] = b_ih1[j] + (j < 512 ? b_hh1[j] : 0.0f);
    if (j >= 512) bhh1n[j - 512] = b_hh1[j];
  }
  for (int j = tid; j < 512; j += NT_) wampL[j] = w_amp[j];
  if (tid < 2) bampL[tid] = b_amp[tid];
  {
    int row = tid >> 2, q = tid & 3;
    const int* xp = x + (size_t)(rowbase + row) * SORB_ + q * 16;
    unsigned m = 0;
    #pragma unroll
    for (int i = 0; i < 16; ++i) m |= (unsigned)(xp[i] & 1) << i;
    bitsL[row * 4 + q] = (unsigned short)m;
  }
  for (int i = tid; i < TB_ * H_; i += NT_) { h0s[i] = (f16)0.f; h1s[i] = (f16)0.f; }
  __syncthreads();

  float prob = 1.0f;
  const f16* Wih1 = W16 + 768 * 256;
  const f16* Whh1 = W16 + 2 * 768 * 256;

  for (int t = -1; t < SORB_; ++t) {
    // ================= layer 0 =================
    for (int mh = 0; mh < 2; ++mh) {          // M-half: rows [mh*64, mh*64+64)
      f16x4 st[8];                             // staged h0_new (f16 packed), [nt*4+m]
      #pragma unroll
      for (int nt = 0; nt < 2; ++nt) {
        const int col = wave * 32 + nt * 16 + l15;   // hidden-unit index 0..255
        f32x4 aR[4], aZ[4], aN[4];
        #pragma unroll
        for (int m = 0; m < 4; ++m) { aR[m] = (f32x4){0,0,0,0}; aZ[m] = aR[m]; aN[m] = aR[m]; }
        #pragma unroll
        for (int kt = 0; kt < 8; ++kt) {
          const int k0 = kt * 32 + lg * 8;
          const f16* wb = W16 + (size_t)col * 256 + k0;      // r-gate row = col
          f16x8 Br = *(const f16x8*)(wb);
          f16x8 Bz = *(const f16x8*)(wb + 256 * 256);
          f16x8 Bn = *(const f16x8*)(wb + 512 * 256);
          #pragma unroll
          for (int m = 0; m < 4; ++m) {
            const int arow = mh * 64 + m * 16 + l15;
            f16x8 A = *(const f16x8*)&h0s[hswz(arow, k0)];
            aR[m] = MFMA16(A, Br, aR[m]);
            aZ[m] = MFMA16(A, Bz, aZ[m]);
            aN[m] = MFMA16(A, Bn, aN[m]);
          }
        }
        #pragma unroll
        for (int m = 0; m < 4; ++m) {
          #pragma unroll
          for (int e = 0; e < 4; ++e) {
            const int row = mh * 64 + m * 16 + lg * 4 + e;   // D: row=(l>>4)*4+reg, col=l&15
            int cse = 0;
            if (t >= 0) cse = 1 + ((bitsL[row * 4 + (t >> 4)] >> (t & 15)) & 1);
            const float* gt = &gi0T[cse * 768];
            float r  = sigm(aR[m][e] + gt[col]);
            float z  = sigm(aZ[m][e] + gt[256 + col]);
            float hn = aN[m][e] + bhh0n[col];
            float n  = tanh_fast(gt[512 + col] + r * hn);
            float ho = (float)h0s[hswz(row, col)];
            st[nt * 4 + m][e] = (f16)((1.0f - z) * n + z * ho);
          }
        }
      }
      __syncthreads();                         // all A-reads of this half done
      #pragma unroll
      for (int nt = 0; nt < 2; ++nt) {
        const int col = wave * 32 + nt * 16 + l15;
        #pragma unroll
        for (int m = 0; m < 4; ++m)
          #pragma unroll
          for (int e = 0; e < 4; ++e) {
            const int row = mh * 64 + m * 16 + lg * 4 + e;
            h0s[hswz(row, col)] = st[nt * 4 + m][e];
          }
      }
      __syncthreads();
    }

    // ================= layer 1 =================
    for (int mh = 0; mh < 2; ++mh) {
      f16x4 st[8];                             // staged h1_new for the whole half
      #pragma unroll
      for (int nt = 0; nt < 2; ++nt) {
        const int col = wave * 32 + nt * 16 + l15;
        #pragma unroll
        for (int ms = 0; ms < 2; ++ms) {       // m-subblock of 2 tiles: acc 64 -> 32 regs
          f32x4 aR[2], aZ[2], aI[2], aHn[2];
          #pragma unroll
          for (int m = 0; m < 2; ++m) { aR[m] = (f32x4){0,0,0,0}; aZ[m] = aR[m]; aI[m] = aR[m]; aHn[m] = aR[m]; }
          #pragma unroll
          for (int kt = 0; kt < 8; ++kt) {
            const int k0 = kt * 32 + lg * 8;
            const f16* wi = Wih1 + (size_t)col * 256 + k0;
            const f16* wh = Whh1 + (size_t)col * 256 + k0;
            f16x8 BiR = *(const f16x8*)(wi);
            f16x8 BiZ = *(const f16x8*)(wi + 256 * 256);
            f16x8 BiN = *(const f16x8*)(wi + 512 * 256);
            f16x8 BhR = *(const f16x8*)(wh);
            f16x8 BhZ = *(const f16x8*)(wh + 256 * 256);
            f16x8 BhN = *(const f16x8*)(wh + 512 * 256);
            #pragma unroll
            for (int mm = 0; mm < 2; ++mm) {
              const int arow = mh * 64 + (ms * 2 + mm) * 16 + l15;
              f16x8 A0 = *(const f16x8*)&h0s[hswz(arow, k0)];  // h0_new
              f16x8 A1 = *(const f16x8*)&h1s[hswz(arow, k0)];  // h1_old
              aR[mm]  = MFMA16(A0, BiR, aR[mm]);  aR[mm] = MFMA16(A1, BhR, aR[mm]);
              aZ[mm]  = MFMA16(A0, BiZ, aZ[mm]);  aZ[mm] = MFMA16(A1, BhZ, aZ[mm]);
              aI[mm]  = MFMA16(A0, BiN, aI[mm]);
              aHn[mm] = MFMA16(A1, BhN, aHn[mm]);
            }
          }
          #pragma unroll
          for (int mm = 0; mm < 2; ++mm) {
            #pragma unroll
            for (int e = 0; e < 4; ++e) {
              float r = sigm(aR[mm][e] + bsum1[col]);
              float z = sigm(aZ[mm][e] + bsum1[256 + col]);
              float n = tanh_fast(aI[mm][e] + bsum1[512 + col] + r * (aHn[mm][e] + bhh1n[col]));
              const int row = mh * 64 + (ms * 2 + mm) * 16 + lg * 4 + e;
              float ho = (float)h1s[hswz(row, col)];
              st[nt * 4 + ms * 2 + mm][e] = (f16)((1.0f - z) * n + z * ho);
            }
          }
        }
      }
      __syncthreads();
      #pragma unroll
      for (int nt = 0; nt < 2; ++nt) {
        const int col = wave * 32 + nt * 16 + l15;
        #pragma unroll
        for (int m = 0; m < 4; ++m)
          #pragma unroll
          for (int e = 0; e < 4; ++e) {
            const int row = mh * 64 + m * 16 + lg * 4 + e;
            h1s[hswz(row, col)] = st[nt * 4 + m][e];
          }
      }
      __syncthreads();
    }

    // ================= amplitude head =================
    if (t >= 0) {
      const int row = tid >> 2;
      const int t4  = tid & 3;
      float d0 = 0.f, d1 = 0.f;
      #pragma unroll
      for (int kk = 0; kk < 64; kk += 8) {
        const int k0 = t4 * 64 + kk;
        f16x8 hv = *(const f16x8*)&h1s[hswz(row, k0)];
        #pragma unroll
        for (int i = 0; i < 8; ++i) {
          float hf = (float)hv[i];
          d0 = fmaf(hf, wampL[k0 + i], d0);
          d1 = fmaf(hf, wampL[256 + k0 + i], d1);
        }
      }
      d0 += __shfl_xor(d0, 1); d0 += __shfl_xor(d0, 2);
      d1 += __shfl_xor(d1, 1); d1 += __shfl_xor(d1, 2);
      const int bit = (bitsL[row * 4 + (t >> 4)] >> (t & 15)) & 1;
      float diff = (d0 + bampL[0]) - (d1 + bampL[1]);
      if (bit) diff = -diff;
      prob *= 1.0f / (1.0f + __expf(-diff));   // softmax over 2 = sigmoid of logit diff
    }
  }

  if ((tid & 3) == 0) out[rowbase + (tid >> 2)] = sqrtf(prob);
}

extern "C" void kernel_launch(void* const* d_in, const int* in_sizes, int n_in,
                              void* d_out, int out_size, void* d_ws, size_t ws_size,
                              hipStream_t stream) {
  const int*   x     = (const int*)d_in[0];
  const float* w_ih0 = (const float*)d_in[1];
  const float* w_hh0 = (const float*)d_in[2];
  const float* b_ih0 = (const float*)d_in[3];
  const float* b_hh0 = (const float*)d_in[4];
  const float* w_ih1 = (const float*)d_in[5];
  const float* w_hh1 = (const float*)d_in[6];
  const float* b_ih1 = (const float*)d_in[7];
  const float* b_hh1 = (const float*)d_in[8];
  const float* w_amp = (const float*)d_in[9];
  const float* b_amp = (const float*)d_in[10];
  (void)in_sizes; (void)n_in; (void)out_size; (void)ws_size;

  f16* W16 = (f16*)d_ws;   // needs 3*768*256*2 = 1.18 MB of workspace
  hipLaunchKernelGGL(wcvt, dim3(768), dim3(256), 0, stream, w_hh0, w_ih1, w_hh1, W16);
  hipLaunchKernelGGL(rnnwf, dim3(256), dim3(NT_), 0, stream,
                     x, w_ih0, b_ih0, b_hh0, b_ih1, b_hh1, w_amp, b_amp, W16,
                     (float*)d_out);
}